// Round 12
// baseline (53.698 us; speedup 1.0000x reference)
//
#include <hip/hip_runtime.h>

#define N_ROWS   1024
#define D_DIM    128
#define C_CLS    50000
#define C_PAD    50048
#define NCT64    782        // 50048/64 column tiles (64 cols each)
#define NG       128        // ct groups; 782 = 6*128 + 14
#define NPART    256        // partials per row = NG * 2 col-halves
#define S_SCALE  30.0f
#define M_MARGIN 0.35f
#define EXP2_SCALE 43.2808512266689f    // 30 * log2(e)  (folded into fhat)
#define EXP2M      15.1482979293341f    // M_MARGIN * EXP2_SCALE
#define LN2        0.6931471805599453f

#define VM4 asm volatile("s_waitcnt vmcnt(4)" ::: "memory")
#define VM2 asm volatile("s_waitcnt vmcnt(2)" ::: "memory")
#define VM0 asm volatile("s_waitcnt vmcnt(0)" ::: "memory")

typedef short s8v __attribute__((ext_vector_type(8)));   // 8 x bf16 bits (4 VGPRs)
typedef float f4v __attribute__((ext_vector_type(4)));

__device__ inline unsigned short f2bf(float f) {
    unsigned u = __float_as_uint(f);
    u += 0x7FFF + ((u >> 16) & 1);      // round-to-nearest-even (inputs are finite)
    return (unsigned short)(u >> 16);
}
__device__ inline float bf2f(unsigned short h) {
    return __uint_as_float(((unsigned)h) << 16);
}
__device__ inline void load_lds16(const char* src, unsigned char* lds) {
    __builtin_amdgcn_global_load_lds(
        (const __attribute__((address_space(1))) void*)src,
        (__attribute__((address_space(3))) void*)lds, 16, 0, 0);
}

// ---------------------------------------------------------------------------
// Row-normalize, float4 (16B/lane), 2 rows per wave (half-wave per row).
// rows [0,C_PAD): weight -> what, unit norm (rows >= C_CLS zeroed).
// rows [C_PAD,+N_ROWS): feature -> fhat, norm SCALED by EXP2_SCALE so the
// GEMM's MFMA output is directly in exp2 units.
// ---------------------------------------------------------------------------
__global__ void norm_rows_fused(const float* __restrict__ weight,
                                const float* __restrict__ feature,
                                unsigned short* __restrict__ what,
                                unsigned short* __restrict__ fhat) {
    int wid = threadIdx.x >> 6, lane = threadIdx.x & 63;
    int half = lane >> 5, l32 = lane & 31;
    int r = blockIdx.x * 8 + wid * 2 + half;

    const float* src;
    unsigned short* dst;
    int srcRow, valid;
    float scale;
    if (r < C_PAD) {
        src = weight; dst = what; srcRow = r; valid = (r < C_CLS); scale = 1.0f;
    } else {
        src = feature; dst = fhat; srcRow = r - C_PAD; valid = 1; scale = EXP2_SCALE;
    }
    float4 v = make_float4(0.f, 0.f, 0.f, 0.f);
    if (valid) v = ((const float4*)src)[(size_t)srcRow * 32 + l32];
    float ss = v.x * v.x + v.y * v.y + v.z * v.z + v.w * v.w;
    #pragma unroll
    for (int s = 1; s < 32; s <<= 1) ss += __shfl_xor(ss, s, 32);
    float inv = valid ? scale / fmaxf(sqrtf(ss), 1e-8f) : 0.f;
    ushort4 o;
    o.x = f2bf(v.x * inv); o.y = f2bf(v.y * inv);
    o.z = f2bf(v.z * inv); o.w = f2bf(v.w * inv);
    ((ushort4*)dst)[(size_t)srcRow * 32 + l32] = o;
}

// ---------------------------------------------------------------------------
// Static body I of the ct-loop: buffer I&3, stage target (I+3)&3.
// Counted vmcnt derived per body (never 0 mid-loop): before body I the
// outstanding stages are tiles I..min(nt-1,I+2) (2 instrs each); wait leaves
// the newer ones in flight. Stage(I+3) issued right after the barrier so its
// ~900cyc HBM latency hides under 3 tiles (~1050cyc) of compute.
// ---------------------------------------------------------------------------
template<int I>
__device__ __forceinline__ void gemm_body(
    unsigned char* __restrict__ smem, const char* __restrict__ bSrc,
    int sOffL, int dOff, const int (&vb)[2][4], const s8v (&afr)[4][4],
    float (&esum)[4][4], int g, int nt, int wcol, int lrow)
{
    constexpr int BUFO  = (I & 3) * 16384;
    constexpr int SBUFO = ((I + 3) & 3) * 16384;

    if constexpr (I <= 3)      { VM4; }
    else if constexpr (I == 4) { if (nt == 7) { VM4; } else { VM2; } }
    else if constexpr (I == 5) { if (nt == 7) { VM2; } else { VM0; } }
    else                       { VM0; }
    __builtin_amdgcn_s_barrier();
    __builtin_amdgcn_sched_barrier(0);

    if constexpr (I <= 3) {                      // stage tile I+3
        if (I <= 2 || nt == 7) {
            const char* src = bSrc + (size_t)(I + 3) * 2097152;  // 128*16384
            load_lds16(src + sOffL,        smem + SBUFO + dOff);
            load_lds16(src + sOffL + 8192, smem + SBUFO + dOff + 8192);
        }
    }

    f4v acc[4][2];
    f4v zero = {0.f, 0.f, 0.f, 0.f};
    #pragma unroll
    for (int m = 0; m < 4; m++) { acc[m][0] = zero; acc[m][1] = zero; }

    #pragma unroll
    for (int kk = 0; kk < 4; kk++) {
        s8v b0 = *(const s8v*)(smem + BUFO + vb[0][kk]);
        s8v b1 = *(const s8v*)(smem + BUFO + vb[1][kk]);
        #pragma unroll
        for (int m = 0; m < 4; m++) {
            acc[m][0] = __builtin_amdgcn_mfma_f32_16x16x32_bf16(afr[kk][m], b0, acc[m][0], 0, 0, 0);
            acc[m][1] = __builtin_amdgcn_mfma_f32_16x16x32_bf16(afr[kk][m], b1, acc[m][1], 0, 0, 0);
        }
    }

    const int ct = g + 128 * I;
    if (ct != NCT64 - 1) {                // fast path (only body 6 of g==13 masks)
        #pragma unroll
        for (int m = 0; m < 4; m++)
            #pragma unroll
            for (int n = 0; n < 2; n++)
                #pragma unroll
                for (int j = 0; j < 4; j++)
                    esum[m][j] += __builtin_amdgcn_exp2f(acc[m][n][j]);
    } else {
        #pragma unroll
        for (int n = 0; n < 2; n++) {
            int gc = ct * 64 + wcol * 32 + n * 16 + lrow;
            #pragma unroll
            for (int m = 0; m < 4; m++)
                #pragma unroll
                for (int j = 0; j < 4; j++)
                    if (gc < C_CLS)
                        esum[m][j] += __builtin_amdgcn_exp2f(acc[m][n][j]);
        }
    }
}

// ---------------------------------------------------------------------------
// ct-loop GEMM+exp: 256-row blocks, 8 waves (4 row-quads x 2 col-halves),
// 64 cols per tile, tiles ct = g + 128*I (6-7, static bodies). A (64KB)
// bounces through smem -> registers. B: 4 x 16KB buffers, 3-deep prefetch,
// counted vmcnt, one s_barrier per tile. All LDS read addrs precomputed
// (vb[2][4] VGPRs + compile-time buffer imms) -> ~zero per-tile addressing
// VALU. XOR swizzle on GLOBAL source (rule #21), linear LDS dest.
// Grid 128 x 4 = 512 blocks = 2/CU (LDS 64KB, 16 waves/CU).
// ---------------------------------------------------------------------------
__global__ __launch_bounds__(512, 4)
void gemm_exp_kernel(const short* __restrict__ fhat,
                     const short* __restrict__ what,
                     float* __restrict__ part2) {
    __shared__ __align__(16) unsigned char smem[65536];   // A prologue OR 4x16KB B
    const int g   = blockIdx.x;           // ct group, 0..127
    const int rt2 = blockIdx.y;           // 256-row tile, 0..3
    const int tid = threadIdx.x;
    const int wid = tid >> 6;
    const int lane = tid & 63;
    const int lrow = lane & 15;
    const int kgrp = lane >> 4;
    const int wrow = wid >> 1;            // row quad (64 rows), 0..3
    const int wcol = wid & 1;             // col half (32 cols)
    const int nt = (g < 14) ? 7 : 6;      // tiles in this group (782 = 6*128+14)

    const char* aSrc = (const char*)fhat + (size_t)rt2 * 65536;
    const char* bSrc = (const char*)what + (size_t)g * 16384;

    // ---- prologue: A tile (64KB, 256 rows) -> smem, then A -> registers ----
    #pragma unroll
    for (int i = 0; i < 8; i++) {
        int o = wid * 8192 + i * 1024 + lane * 16;
        int s = o ^ (((o >> 8) & 7) << 4);      // source pre-swizzle (involution)
        load_lds16(aSrc + s, smem + o);
    }
    __syncthreads();

    s8v afr[4][4];                        // wave rows: wrow*64 + m*16 + lrow
    #pragma unroll
    for (int kk = 0; kk < 4; kk++)
        #pragma unroll
        for (int m = 0; m < 4; m++) {
            int row = wrow * 64 + m * 16 + lrow;
            int b = (row * 256 + kk * 64 + kgrp * 16) ^ ((row & 7) << 4);
            afr[kk][m] = *(const s8v*)(smem + b);
        }
    __syncthreads();                      // afr reads retired; smem reusable

    // ---- precomputed addressing (loop-invariant) ----
    const int dOff  = wid * 1024 + lane * 16;              // stage LDS dest (instr0)
    const int sOffL = dOff ^ (((dOff >> 8) & 7) << 4);     // stage src (instr0); +8192 invariant
    int vb[2][4];                                          // B ds_read addrs within buf
    #pragma unroll
    for (int n = 0; n < 2; n++)
        #pragma unroll
        for (int kk = 0; kk < 4; kk++) {
            int row = wcol * 32 + n * 16 + lrow;
            vb[n][kk] = (row * 256 + kk * 64 + kgrp * 16) ^ ((row & 7) << 4);
        }

    // ---- stage tiles 0,1,2 -> bufs 0,1,2 (2 instrs each) ----
    #pragma unroll
    for (int tt = 0; tt < 3; ++tt) {
        const char* src = bSrc + (size_t)tt * 2097152;
        load_lds16(src + sOffL,        smem + tt * 16384 + dOff);
        load_lds16(src + sOffL + 8192, smem + tt * 16384 + dOff + 8192);
    }

    float esum[4][4];
    #pragma unroll
    for (int m = 0; m < 4; m++)
        #pragma unroll
        for (int j = 0; j < 4; j++) esum[m][j] = 0.f;

    gemm_body<0>(smem, bSrc, sOffL, dOff, vb, afr, esum, g, nt, wcol, lrow);
    gemm_body<1>(smem, bSrc, sOffL, dOff, vb, afr, esum, g, nt, wcol, lrow);
    gemm_body<2>(smem, bSrc, sOffL, dOff, vb, afr, esum, g, nt, wcol, lrow);
    gemm_body<3>(smem, bSrc, sOffL, dOff, vb, afr, esum, g, nt, wcol, lrow);
    gemm_body<4>(smem, bSrc, sOffL, dOff, vb, afr, esum, g, nt, wcol, lrow);
    gemm_body<5>(smem, bSrc, sOffL, dOff, vb, afr, esum, g, nt, wcol, lrow);
    if (nt == 7)
        gemm_body<6>(smem, bSrc, sOffL, dOff, vb, afr, esum, g, nt, wcol, lrow);

    // ---- epilogue: reduce over the wave's 16 col-lanes, direct write ----
    #pragma unroll
    for (int m = 0; m < 4; m++)
        #pragma unroll
        for (int j = 0; j < 4; j++) {
            float v = esum[m][j];
            v += __shfl_xor(v, 1, 64);
            v += __shfl_xor(v, 2, 64);
            v += __shfl_xor(v, 4, 64);
            v += __shfl_xor(v, 8, 64);
            if (lrow == 0) {
                int row = rt2 * 256 + wrow * 64 + m * 16 + kgrp * 4 + j;
                part2[(size_t)row * NPART + g * 2 + wcol] = v;
            }
        }
}

// ---------------------------------------------------------------------------
// One wave per row: S_n = sum of 256 partials (4 per lane). cys = fp32 dot of
// the SAME bf16 vectors = EXP2_SCALE*cos_y, so Sp = S - exp2(cys) +
// exp2(cys - EXP2M); rowval[n] = (ln(Sp) - LN2*t2)/N + 0.005*||f_n - w_y||^2
// ---------------------------------------------------------------------------
__global__ void finalize_rows_kernel(const float* __restrict__ part2,
                                     const unsigned short* __restrict__ fhat,
                                     const unsigned short* __restrict__ what,
                                     const float* __restrict__ feature,
                                     const float* __restrict__ weight,
                                     const int* __restrict__ label,
                                     float* __restrict__ rowval) {
    int wid = threadIdx.x >> 6, lane = threadIdx.x & 63;
    int n = blockIdx.x * 4 + wid;
    int y = label[n];

    const float* p = part2 + (size_t)n * NPART;
    float S = p[lane] + p[64 + lane] + p[128 + lane] + p[192 + lane];

    float2 f2 = ((const float2*)feature)[(size_t)n * 64 + lane];
    float2 w2 = ((const float2*)weight)[(size_t)y * 64 + lane];
    float dx = f2.x - w2.x, dy = f2.y - w2.y;
    float cl = dx * dx + dy * dy;

    ushort2 fh = ((const ushort2*)fhat)[(size_t)n * 64 + lane];
    ushort2 wh = ((const ushort2*)what)[(size_t)y * 64 + lane];
    float cys = bf2f(fh.x) * bf2f(wh.x) + bf2f(fh.y) * bf2f(wh.y);

    #pragma unroll
    for (int s = 1; s < 64; s <<= 1) {
        S   += __shfl_xor(S, s, 64);
        cl  += __shfl_xor(cl, s, 64);
        cys += __shfl_xor(cys, s, 64);
    }
    if (lane == 0) {
        float t2 = cys - EXP2M;
        float Sp = S - __builtin_amdgcn_exp2f(cys) + __builtin_amdgcn_exp2f(t2);
        rowval[n] = (logf(Sp) - LN2 * t2) * (1.0f / (float)N_ROWS) + 0.005f * cl;
    }
}

__global__ void reduce_final_kernel(const float* __restrict__ rowval, float* __restrict__ out) {
    __shared__ float sbuf[4];
    int t = threadIdx.x;
    float v = rowval[t] + rowval[t + 256] + rowval[t + 512] + rowval[t + 768];
    #pragma unroll
    for (int s = 1; s < 64; s <<= 1) v += __shfl_xor(v, s, 64);
    if ((t & 63) == 0) sbuf[t >> 6] = v;
    __syncthreads();
    if (t == 0) out[0] = sbuf[0] + sbuf[1] + sbuf[2] + sbuf[3];
}

// ---------------------------------------------------------------------------
extern "C" void kernel_launch(void* const* d_in, const int* in_sizes, int n_in,
                              void* d_out, int out_size, void* d_ws, size_t ws_size,
                              hipStream_t stream) {
    const float* feature = (const float*)d_in[0];
    const float* weight  = (const float*)d_in[1];
    const int*   label   = (const int*)d_in[2];

    // Workspace layout (bytes):
    //   what   [0,        12812288)  : 50048*128*2
    //   fhat   [12812288, 13074432)  : 1024*128*2
    //   part2  [13074432, 14123008)  : 1024*256*4
    //   rowval [14123008, 14127104)  : 1024*4
    const size_t WS_NEEDED = 14127104;
    if (ws_size < WS_NEEDED) return;   // defensive: visible failure, not OOB writes

    char* ws = (char*)d_ws;
    unsigned short* what = (unsigned short*)ws;
    unsigned short* fhat = (unsigned short*)(ws + 12812288);
    float*         part2 = (float*)(ws + 13074432);
    float*        rowval = (float*)(ws + 14123008);

    norm_rows_fused<<<dim3((C_PAD + N_ROWS) / 8), 256, 0, stream>>>(weight, feature, what, fhat);
    gemm_exp_kernel<<<dim3(NG, 4), 512, 0, stream>>>((const short*)fhat, (const short*)what, part2);
    finalize_rows_kernel<<<dim3(N_ROWS / 4), 256, 0, stream>>>(part2, fhat, what, feature, weight,
                                                               label, rowval);
    reduce_final_kernel<<<1, 256, 0, stream>>>(rowval, (float*)d_out);
}

// Round 13
// 37.987 us; speedup vs baseline: 1.4136x; 1.4136x over previous
//
#include <hip/hip_runtime.h>

#define N_ROWS   1024
#define D_DIM    128
#define C_CLS    50000
#define C_PAD    50048
#define NCT64    782        // 50048/64 column tiles (64 cols each)
#define NG       128        // ct groups; 782 = 6*128 + 14
#define NPART    256        // partials per row = NG * 2 col-halves
#define S_SCALE  30.0f
#define M_MARGIN 0.35f
#define EXP2_SCALE 43.2808512266689f    // 30 * log2(e)  (folded into fhat)
#define EXP2M      15.1482979293341f    // M_MARGIN * EXP2_SCALE
#define LN2        0.6931471805599453f

#define VM4 asm volatile("s_waitcnt vmcnt(4)" ::: "memory")
#define VM2 asm volatile("s_waitcnt vmcnt(2)" ::: "memory")
#define VM0 asm volatile("s_waitcnt vmcnt(0)" ::: "memory")

typedef short s8v __attribute__((ext_vector_type(8)));   // 8 x bf16 bits (4 VGPRs)
typedef float f4v __attribute__((ext_vector_type(4)));

__device__ inline unsigned short f2bf(float f) {
    unsigned u = __float_as_uint(f);
    u += 0x7FFF + ((u >> 16) & 1);      // round-to-nearest-even (inputs are finite)
    return (unsigned short)(u >> 16);
}
__device__ inline float bf2f(unsigned short h) {
    return __uint_as_float(((unsigned)h) << 16);
}
__device__ inline void load_lds16(const char* src, unsigned char* lds) {
    __builtin_amdgcn_global_load_lds(
        (const __attribute__((address_space(1))) void*)src,
        (__attribute__((address_space(3))) void*)lds, 16, 0, 0);
}

// ---------------------------------------------------------------------------
// Row-normalize, float4 (16B/lane), 2 rows per wave (half-wave per row).
// rows [0,C_PAD): weight -> what, unit norm (rows >= C_CLS zeroed).
// rows [C_PAD,+N_ROWS): feature -> fhat, norm SCALED by EXP2_SCALE so the
// GEMM's MFMA output is directly in exp2 units.
// ---------------------------------------------------------------------------
__global__ void norm_rows_fused(const float* __restrict__ weight,
                                const float* __restrict__ feature,
                                unsigned short* __restrict__ what,
                                unsigned short* __restrict__ fhat) {
    int wid = threadIdx.x >> 6, lane = threadIdx.x & 63;
    int half = lane >> 5, l32 = lane & 31;
    int r = blockIdx.x * 8 + wid * 2 + half;

    const float* src;
    unsigned short* dst;
    int srcRow, valid;
    float scale;
    if (r < C_PAD) {
        src = weight; dst = what; srcRow = r; valid = (r < C_CLS); scale = 1.0f;
    } else {
        src = feature; dst = fhat; srcRow = r - C_PAD; valid = 1; scale = EXP2_SCALE;
    }
    float4 v = make_float4(0.f, 0.f, 0.f, 0.f);
    if (valid) v = ((const float4*)src)[(size_t)srcRow * 32 + l32];
    float ss = v.x * v.x + v.y * v.y + v.z * v.z + v.w * v.w;
    #pragma unroll
    for (int s = 1; s < 32; s <<= 1) ss += __shfl_xor(ss, s, 32);
    float inv = valid ? scale / fmaxf(sqrtf(ss), 1e-8f) : 0.f;
    ushort4 o;
    o.x = f2bf(v.x * inv); o.y = f2bf(v.y * inv);
    o.z = f2bf(v.z * inv); o.w = f2bf(v.w * inv);
    ((ushort4*)dst)[(size_t)srcRow * 32 + l32] = o;
}

// ---------------------------------------------------------------------------
// Static body I of the ct-loop: buffer I&3, stage target (I+3)&3.
// Counted vmcnt derived per body (never 0 mid-loop): before body I the
// outstanding stages are tiles I..min(nt-1,I+2) (2 instrs each); wait leaves
// the newer ones in flight. Stage(I+3) issued right after the barrier so its
// ~900cyc HBM latency hides under 3 tiles (~1050cyc) of compute.
// NOTE: counted vmcnt is only sound with ZERO scratch spills (scratch ops
// also increment vmcnt) -- hence the (512,2) launch bound below.
// ---------------------------------------------------------------------------
template<int I>
__device__ __forceinline__ void gemm_body(
    unsigned char* __restrict__ smem, const char* __restrict__ bSrc,
    int sOffL, int dOff, const int (&vb)[2][4], const s8v (&afr)[4][4],
    float (&esum)[4][4], int g, int nt, int wcol, int lrow)
{
    constexpr int BUFO  = (I & 3) * 16384;
    constexpr int SBUFO = ((I + 3) & 3) * 16384;

    if constexpr (I <= 3)      { VM4; }
    else if constexpr (I == 4) { if (nt == 7) { VM4; } else { VM2; } }
    else if constexpr (I == 5) { if (nt == 7) { VM2; } else { VM0; } }
    else                       { VM0; }
    __builtin_amdgcn_s_barrier();
    __builtin_amdgcn_sched_barrier(0);

    if constexpr (I <= 3) {                      // stage tile I+3
        if (I <= 2 || nt == 7) {
            const char* src = bSrc + (size_t)(I + 3) * 2097152;  // 128*16384
            load_lds16(src + sOffL,        smem + SBUFO + dOff);
            load_lds16(src + sOffL + 8192, smem + SBUFO + dOff + 8192);
        }
    }

    f4v acc[4][2];
    f4v zero = {0.f, 0.f, 0.f, 0.f};
    #pragma unroll
    for (int m = 0; m < 4; m++) { acc[m][0] = zero; acc[m][1] = zero; }

    #pragma unroll
    for (int kk = 0; kk < 4; kk++) {
        s8v b0 = *(const s8v*)(smem + BUFO + vb[0][kk]);
        s8v b1 = *(const s8v*)(smem + BUFO + vb[1][kk]);
        #pragma unroll
        for (int m = 0; m < 4; m++) {
            acc[m][0] = __builtin_amdgcn_mfma_f32_16x16x32_bf16(afr[kk][m], b0, acc[m][0], 0, 0, 0);
            acc[m][1] = __builtin_amdgcn_mfma_f32_16x16x32_bf16(afr[kk][m], b1, acc[m][1], 0, 0, 0);
        }
    }

    const int ct = g + 128 * I;
    if (ct != NCT64 - 1) {                // fast path (only body 6 of g==13 masks)
        #pragma unroll
        for (int m = 0; m < 4; m++)
            #pragma unroll
            for (int n = 0; n < 2; n++)
                #pragma unroll
                for (int j = 0; j < 4; j++)
                    esum[m][j] += __builtin_amdgcn_exp2f(acc[m][n][j]);
    } else {
        #pragma unroll
        for (int n = 0; n < 2; n++) {
            int gc = ct * 64 + wcol * 32 + n * 16 + lrow;
            #pragma unroll
            for (int m = 0; m < 4; m++)
                #pragma unroll
                for (int j = 0; j < 4; j++)
                    if (gc < C_CLS)
                        esum[m][j] += __builtin_amdgcn_exp2f(acc[m][n][j]);
        }
    }
}

// ---------------------------------------------------------------------------
// ct-loop GEMM+exp: 256-row blocks, 8 waves (4 row-quads x 2 col-halves),
// 64 cols per tile, tiles ct = g + 128*I (6-7, static bodies). A (64KB)
// bounces through smem -> registers. B: 4 x 16KB buffers, 3-deep prefetch,
// counted vmcnt, one s_barrier per tile. All LDS read addrs precomputed
// (vb[2][4] VGPRs + compile-time buffer imms) -> ~zero per-tile addressing
// VALU. XOR swizzle on GLOBAL source (rule #21), linear LDS dest.
// __launch_bounds__(512,2): SESSION RULE -- requesting >=4 waves/EU coerces
// the allocator to 64 arch VGPRs and spills (r10: 45MB, r12: 49MB scratch
// writes, MfmaUtil ~9%). At (512,2) the cap is ~256, the kernel allocates
// its natural ~116 spill-free, and HW still resides 2 blocks/CU (LDS-bound)
// = 16 waves/CU since 116 <= 128-VGPR step.
// Grid 128 x 4 = 512 blocks = 2/CU.
// ---------------------------------------------------------------------------
__global__ __launch_bounds__(512, 2)
void gemm_exp_kernel(const short* __restrict__ fhat,
                     const short* __restrict__ what,
                     float* __restrict__ part2) {
    __shared__ __align__(16) unsigned char smem[65536];   // A prologue OR 4x16KB B
    const int g   = blockIdx.x;           // ct group, 0..127
    const int rt2 = blockIdx.y;           // 256-row tile, 0..3
    const int tid = threadIdx.x;
    const int wid = tid >> 6;
    const int lane = tid & 63;
    const int lrow = lane & 15;
    const int kgrp = lane >> 4;
    const int wrow = wid >> 1;            // row quad (64 rows), 0..3
    const int wcol = wid & 1;             // col half (32 cols)
    const int nt = (g < 14) ? 7 : 6;      // tiles in this group (782 = 6*128+14)

    const char* aSrc = (const char*)fhat + (size_t)rt2 * 65536;
    const char* bSrc = (const char*)what + (size_t)g * 16384;

    // ---- prologue: A tile (64KB, 256 rows) -> smem, then A -> registers ----
    #pragma unroll
    for (int i = 0; i < 8; i++) {
        int o = wid * 8192 + i * 1024 + lane * 16;
        int s = o ^ (((o >> 8) & 7) << 4);      // source pre-swizzle (involution)
        load_lds16(aSrc + s, smem + o);
    }
    __syncthreads();

    s8v afr[4][4];                        // wave rows: wrow*64 + m*16 + lrow
    #pragma unroll
    for (int kk = 0; kk < 4; kk++)
        #pragma unroll
        for (int m = 0; m < 4; m++) {
            int row = wrow * 64 + m * 16 + lrow;
            int b = (row * 256 + kk * 64 + kgrp * 16) ^ ((row & 7) << 4);
            afr[kk][m] = *(const s8v*)(smem + b);
        }
    __syncthreads();                      // afr reads retired; smem reusable

    // ---- precomputed addressing (loop-invariant) ----
    const int dOff  = wid * 1024 + lane * 16;              // stage LDS dest (instr0)
    const int sOffL = dOff ^ (((dOff >> 8) & 7) << 4);     // stage src (instr0); +8192 invariant
    int vb[2][4];                                          // B ds_read addrs within buf
    #pragma unroll
    for (int n = 0; n < 2; n++)
        #pragma unroll
        for (int kk = 0; kk < 4; kk++) {
            int row = wcol * 32 + n * 16 + lrow;
            vb[n][kk] = (row * 256 + kk * 64 + kgrp * 16) ^ ((row & 7) << 4);
        }

    // ---- stage tiles 0,1,2 -> bufs 0,1,2 (2 instrs each) ----
    #pragma unroll
    for (int tt = 0; tt < 3; ++tt) {
        const char* src = bSrc + (size_t)tt * 2097152;
        load_lds16(src + sOffL,        smem + tt * 16384 + dOff);
        load_lds16(src + sOffL + 8192, smem + tt * 16384 + dOff + 8192);
    }

    float esum[4][4];
    #pragma unroll
    for (int m = 0; m < 4; m++)
        #pragma unroll
        for (int j = 0; j < 4; j++) esum[m][j] = 0.f;

    gemm_body<0>(smem, bSrc, sOffL, dOff, vb, afr, esum, g, nt, wcol, lrow);
    gemm_body<1>(smem, bSrc, sOffL, dOff, vb, afr, esum, g, nt, wcol, lrow);
    gemm_body<2>(smem, bSrc, sOffL, dOff, vb, afr, esum, g, nt, wcol, lrow);
    gemm_body<3>(smem, bSrc, sOffL, dOff, vb, afr, esum, g, nt, wcol, lrow);
    gemm_body<4>(smem, bSrc, sOffL, dOff, vb, afr, esum, g, nt, wcol, lrow);
    gemm_body<5>(smem, bSrc, sOffL, dOff, vb, afr, esum, g, nt, wcol, lrow);
    if (nt == 7)
        gemm_body<6>(smem, bSrc, sOffL, dOff, vb, afr, esum, g, nt, wcol, lrow);

    // ---- epilogue: reduce over the wave's 16 col-lanes, direct write ----
    #pragma unroll
    for (int m = 0; m < 4; m++)
        #pragma unroll
        for (int j = 0; j < 4; j++) {
            float v = esum[m][j];
            v += __shfl_xor(v, 1, 64);
            v += __shfl_xor(v, 2, 64);
            v += __shfl_xor(v, 4, 64);
            v += __shfl_xor(v, 8, 64);
            if (lrow == 0) {
                int row = rt2 * 256 + wrow * 64 + m * 16 + kgrp * 4 + j;
                part2[(size_t)row * NPART + g * 2 + wcol] = v;
            }
        }
}

// ---------------------------------------------------------------------------
// One wave per row: S_n = sum of 256 partials (4 per lane). cys = fp32 dot of
// the SAME bf16 vectors = EXP2_SCALE*cos_y, so Sp = S - exp2(cys) +
// exp2(cys - EXP2M); rowval[n] = (ln(Sp) - LN2*t2)/N + 0.005*||f_n - w_y||^2
// ---------------------------------------------------------------------------
__global__ void finalize_rows_kernel(const float* __restrict__ part2,
                                     const unsigned short* __restrict__ fhat,
                                     const unsigned short* __restrict__ what,
                                     const float* __restrict__ feature,
                                     const float* __restrict__ weight,
                                     const int* __restrict__ label,
                                     float* __restrict__ rowval) {
    int wid = threadIdx.x >> 6, lane = threadIdx.x & 63;
    int n = blockIdx.x * 4 + wid;
    int y = label[n];

    const float* p = part2 + (size_t)n * NPART;
    float S = p[lane] + p[64 + lane] + p[128 + lane] + p[192 + lane];

    float2 f2 = ((const float2*)feature)[(size_t)n * 64 + lane];
    float2 w2 = ((const float2*)weight)[(size_t)y * 64 + lane];
    float dx = f2.x - w2.x, dy = f2.y - w2.y;
    float cl = dx * dx + dy * dy;

    ushort2 fh = ((const ushort2*)fhat)[(size_t)n * 64 + lane];
    ushort2 wh = ((const ushort2*)what)[(size_t)y * 64 + lane];
    float cys = bf2f(fh.x) * bf2f(wh.x) + bf2f(fh.y) * bf2f(wh.y);

    #pragma unroll
    for (int s = 1; s < 64; s <<= 1) {
        S   += __shfl_xor(S, s, 64);
        cl  += __shfl_xor(cl, s, 64);
        cys += __shfl_xor(cys, s, 64);
    }
    if (lane == 0) {
        float t2 = cys - EXP2M;
        float Sp = S - __builtin_amdgcn_exp2f(cys) + __builtin_amdgcn_exp2f(t2);
        rowval[n] = (logf(Sp) - LN2 * t2) * (1.0f / (float)N_ROWS) + 0.005f * cl;
    }
}

__global__ void reduce_final_kernel(const float* __restrict__ rowval, float* __restrict__ out) {
    __shared__ float sbuf[4];
    int t = threadIdx.x;
    float v = rowval[t] + rowval[t + 256] + rowval[t + 512] + rowval[t + 768];
    #pragma unroll
    for (int s = 1; s < 64; s <<= 1) v += __shfl_xor(v, s, 64);
    if ((t & 63) == 0) sbuf[t >> 6] = v;
    __syncthreads();
    if (t == 0) out[0] = sbuf[0] + sbuf[1] + sbuf[2] + sbuf[3];
}

// ---------------------------------------------------------------------------
extern "C" void kernel_launch(void* const* d_in, const int* in_sizes, int n_in,
                              void* d_out, int out_size, void* d_ws, size_t ws_size,
                              hipStream_t stream) {
    const float* feature = (const float*)d_in[0];
    const float* weight  = (const float*)d_in[1];
    const int*   label   = (const int*)d_in[2];

    // Workspace layout (bytes):
    //   what   [0,        12812288)  : 50048*128*2
    //   fhat   [12812288, 13074432)  : 1024*128*2
    //   part2  [13074432, 14123008)  : 1024*256*4
    //   rowval [14123008, 14127104)  : 1024*4
    const size_t WS_NEEDED = 14127104;
    if (ws_size < WS_NEEDED) return;   // defensive: visible failure, not OOB writes

    char* ws = (char*)d_ws;
    unsigned short* what = (unsigned short*)ws;
    unsigned short* fhat = (unsigned short*)(ws + 12812288);
    float*         part2 = (float*)(ws + 13074432);
    float*        rowval = (float*)(ws + 14123008);

    norm_rows_fused<<<dim3((C_PAD + N_ROWS) / 8), 256, 0, stream>>>(weight, feature, what, fhat);
    gemm_exp_kernel<<<dim3(NG, 4), 512, 0, stream>>>((const short*)fhat, (const short*)what, part2);
    finalize_rows_kernel<<<dim3(N_ROWS / 4), 256, 0, stream>>>(part2, fhat, what, feature, weight,
                                                               label, rowval);
    reduce_final_kernel<<<1, 256, 0, stream>>>(rowval, (float*)d_out);
}